// Round 16
// baseline (600.758 us; speedup 1.0000x reference)
//
#include <hip/hip_runtime.h>
#include <math.h>

#define TT 160
#define EE 256
#define HH 512
#define KK 768
#define B2 512
#define BQ 256
#define N4 2048

typedef __attribute__((ext_vector_type(8)))  _Float16 half8;
typedef __attribute__((ext_vector_type(16))) float f32x16;

__device__ inline unsigned short f2h(float x){ union{_Float16 h; unsigned short u;}v; v.h=(_Float16)x; return v.u; }
__device__ inline float h2f(unsigned short u){ union{_Float16 h; unsigned short u;}v; v.u=u; return (float)v.h; }
__device__ inline unsigned int packh2(float a,float b){ union{_Float16 h[2]; unsigned int u;}v; v.h[0]=(_Float16)a; v.h[1]=(_Float16)b; return v.u; }

#define LOG2E 1.44269504088896f
__device__ inline float sigmf(float x){
    return __builtin_amdgcn_rcpf(1.0f + __builtin_amdgcn_exp2f(-LOG2E * x));
}
__device__ inline float tanhfast(float x){
    return 1.0f - 2.0f * __builtin_amdgcn_rcpf(__builtin_amdgcn_exp2f(2.0f * LOG2E * x) + 1.0f);
}

// cached (L1/L2) global->LDS, 16B/lane
__device__ inline void gload_lds16_c(const void* g, void* l){
    __builtin_amdgcn_global_load_lds(
        (const __attribute__((address_space(1))) void*)g,
        (__attribute__((address_space(3))) void*)l, 16, 0, 0);
}
// device-coherent global->LDS: SC0|SC1 (read the coherence point)
__device__ inline void gload_lds16_sc(const void* g, void* l){
    __builtin_amdgcn_global_load_lds(
        (const __attribute__((address_space(1))) void*)g,
        (__attribute__((address_space(3))) void*)l, 16, 0, 0x11);
}

// ---------------------------------------------------------------------------
// Wt[unit*4+gate][k] = fp16(W[k][gate*512+unit])   (gates interleaved per unit)
__global__ __launch_bounds__(256) void transposeW(const float* __restrict__ W,
                                                  unsigned short* __restrict__ Wt) {
    __shared__ float tile[32][33];
    const int tx = threadIdx.x & 31, ty = threadIdx.x >> 5;
    const int cb = blockIdx.x * 32;
    const int kb = blockIdx.y * 32;
    #pragma unroll
    for (int j = 0; j < 4; j++)
        tile[ty + j * 8][tx] = W[(size_t)(kb + ty + j * 8) * N4 + cb + tx];
    __syncthreads();
    #pragma unroll
    for (int j = 0; j < 4; j++) {
        int cl = ty + j * 8;
        int col = cb + cl;
        int gate = col >> 9, unit = col & 511;
        Wt[(size_t)(unit * 4 + gate) * KK + kb + tx] = f2h(tile[tx][cl]);
    }
}

// ---------------------------------------------------------------------------
// xseq[t*512+row][k] = fp16(emb[ids[row][t]][k])  — one wave per (t,row)
__global__ __launch_bounds__(256) void xprep(const float* __restrict__ emb,
                                             const int* __restrict__ qids,
                                             const int* __restrict__ rids,
                                             unsigned short* __restrict__ xseq) {
    const int widx = blockIdx.x * 4 + (threadIdx.x >> 6);
    const int lane = threadIdx.x & 63;
    const int row  = widx & 511;
    const int t    = widx >> 9;
    const int id   = (row < BQ) ? qids[row * TT + t] : rids[(row - BQ) * TT + t];
    const float4 f = *(const float4*)&emb[(size_t)id * EE + lane * 4];
    *(uint2*)&xseq[(size_t)widx * EE + lane * 4] =
        make_uint2(packh2(f.x, f.y), packh2(f.z, f.w));
}

// ---------------------------------------------------------------------------
// Persistent LSTM (r12 protocol, barrier-thinned to 3/step).
// 256 blocks x 512 threads (8 waves = 2/SIMD). Block (g=bid&7, bc=bid>>3):
// rows [g*64,+64), units [bc*16,+16). Wave (wr,wc,kg): rows wr*32,
// cols' wc*32, K-half kg. W K-half register-resident (24 half8 = 96 VGPR).
// Step: P(all-wave coalesced flag poll) -> S(h stages issue; IF$ latency
// hides under X) -> X(x MFMAs) -> SYNC-1 -> C(h MFMAs) -> Sx(x(t+1) stage)
// -> D(zb partials) -> SYNC-2 -> E(cell + agent h-store) -> SYNC-3(drain)
// -> F(flag post). WAR chains: bufs2-5 last read < SYNC-2(t-1) < S(t);
// bufs0,1 written Sx(t) after last read X(t) < SYNC-1(t); zb write D(t)
// after E(t-1) < SYNC-3(t-1). Producer/consumer ordering identical to r12:
// h stores drained at SYNC-3 strictly before flag post.
__global__ __launch_bounds__(512, 1) void lstm_persist(
    const unsigned short* __restrict__ Wt,
    const unsigned short* __restrict__ xseq,
    const float* __restrict__ bias,
    const float* __restrict__ wi_, const float* __restrict__ wf_,
    const float* __restrict__ wo_,
    const int* __restrict__ qlen, const int* __restrict__ rlen,
    unsigned short* __restrict__ hbA, unsigned short* __restrict__ hbB,
    unsigned int* __restrict__ bar)   // bar[g*64 + bc] = flags; 8 groups
{
    extern __shared__ char smem[];              // 6*16KB bufs + 2*16KB zb
    float* zb0 = (float*)(smem + 98304);        // [64][64] f32, f4-col swz (kg=0)
    float* zb1 = zb0 + 4096;                    // (kg=1)

    const int tid = threadIdx.x;
    const int bid = blockIdx.x;
    const int g   = bid & 7;
    const int bc  = bid >> 3;
    const int rb  = g * 64;
    unsigned int* gflags = bar + g * 64;
    const int l = tid & 63, w = tid >> 6;
    const int wr = (w >> 2) & 1, wc = (w >> 1) & 1, kg = w & 1;

    // ---- resident W fragments: wave's 32 cols' x its K-half (24 half8)
    half8 wfrag[24];
    {
        const int colp = bc * 64 + wc * 32 + (l & 31);
        const unsigned short* wrow = Wt + (size_t)colp * KK + kg * 64 + (l >> 5) * 8;
        #pragma unroll
        for (int c = 0; c < 6; c++)
            #pragma unroll
            for (int f4 = 0; f4 < 4; f4++)
                wfrag[c * 4 + f4] = *(const half8*)(wrow + c * 128 + f4 * 16);
    }

    // ---- epilogue: thread owns 1 row (erow) x 2 contiguous units
    const int erow = tid >> 3;
    const int eu0  = (tid & 7) * 2;
    const int Ug0  = bc * 16 + eu0;
    const float bi0 = bias[Ug0],        bi1 = bias[Ug0 + 1];
    const float bj0 = bias[HH + Ug0],   bj1 = bias[HH + Ug0 + 1];
    const float bf0 = bias[2*HH + Ug0], bf1 = bias[2*HH + Ug0 + 1];
    const float bo0 = bias[3*HH + Ug0], bo1 = bias[3*HH + Ug0 + 1];
    const float wi0 = wi_[Ug0], wi1 = wi_[Ug0 + 1];
    const float wf0 = wf_[Ug0], wf1 = wf_[Ug0 + 1];
    const float wo0 = wo_[Ug0], wo1 = wo_[Ug0 + 1];
    const int len = (rb + erow < BQ) ? qlen[rb + erow] : rlen[rb + erow - BQ];
    float cc[2] = {0.f, 0.f}, hh[2] = {0.f, 0.f};

    // stage K-chunk tk of step tt into buf tk. Wave w stages rows [w*8,+8).
    // LDS dest linear; XOR-swizzle folded into per-lane SOURCE address.
    auto stage = [&](int tk, int tt, const unsigned short* hsrc) {
        char* base = smem + tk * 16384;
        #pragma unroll
        for (int i2 = 0; i2 < 2; i2++) {
            const int rowbase = w * 8 + i2 * 4;
            const int row = rowbase + (l >> 4);
            const int cch = l & 15;
            const int srcElem = (cch ^ (row & 15)) << 3;
            if (tk < 2) {
                const unsigned short* src =
                    xseq + ((size_t)(tt * B2 + rb + row) * EE + tk * 128 + srcElem);
                gload_lds16_c(src, base + rowbase * 256);
            } else {
                const unsigned short* src =
                    hsrc + ((size_t)(rb + row) * HH + (tk - 2) * 128 + srcElem);
                gload_lds16_sc(src, base + rowbase * 256);
            }
        }
    };

    // wave computes its K-half of chunk tk: 4 MFMAs
    auto compute = [&](int tk, f32x16* a0, f32x16* a1) {
        const char* Ab = smem + tk * 16384;
        const int ra = wr * 32 + (l & 31);
        #pragma unroll
        for (int f4 = 0; f4 < 4; f4++) {
            const int kc = kg * 8 + f4 * 2 + (l >> 5);
            half8 av = *(const half8*)(Ab + ra * 256 + ((kc ^ (ra & 15)) << 4));
            if (f4 & 1) *a1 = __builtin_amdgcn_mfma_f32_32x32x16_f16(av, wfrag[tk * 4 + f4], *a1, 0, 0, 0);
            else        *a0 = __builtin_amdgcn_mfma_f32_32x32x16_f16(av, wfrag[tk * 4 + f4], *a0, 0, 0, 0);
        }
    };

    // prologue: stage step-0 x chunks
    stage(0, 0, hbA);
    stage(1, 0, hbA);
    __syncthreads();

    #pragma unroll 1
    for (int t = 0; t < TT; t++) {
        const unsigned short* hbp = (t & 1) ? hbB : hbA;
        unsigned short* hbq       = (t & 1) ? hbA : hbB;
        f32x16 acc0 = {0,0,0,0,0,0,0,0,0,0,0,0,0,0,0,0};
        f32x16 acc1 = {0,0,0,0,0,0,0,0,0,0,0,0,0,0,0,0};

        // P: every wave certifies h(t) availability itself (coalesced poll
        // of the 32 group flags; 16 redundant 32-lane reads per block)
        if (t > 0) {
            while (__hip_atomic_load(&gflags[tid & 31], __ATOMIC_RELAXED,
                                     __HIP_MEMORY_SCOPE_AGENT) < (unsigned)t)
                __builtin_amdgcn_s_sleep(1);
        }

        // S: issue h stages NOW — IF$ latency hides under X's MFMAs
        stage(2, t, hbp);
        stage(3, t, hbp);
        stage(4, t, hbp);
        stage(5, t, hbp);

        // X: x-part MFMAs on bufs 0,1 (staged last step, drained SYNC-2(t-1))
        compute(0, &acc0, &acc1);
        compute(1, &acc0, &acc1);
        __syncthreads();                       // SYNC-1: h staged, X done

        // C: h-part MFMAs (W resident; 2 waves/SIMD hide ds_read latency)
        compute(2, &acc0, &acc1);
        compute(3, &acc0, &acc1);
        compute(4, &acc0, &acc1);
        compute(5, &acc0, &acc1);

        // Sx: x(t+1) into bufs 0,1 (read-complete at SYNC-1; drains SYNC-2)
        if (t < TT - 1) {
            stage(0, t + 1, hbp);
            stage(1, t + 1, hbp);
        }

        // D: z partials into per-K-half regions, float4-column XOR swizzle
        {
            float* zbk = kg ? zb1 : zb0;
            const int colb = wc * 32 + (l & 31);
            const int c4i = colb >> 2, cr = colb & 3;
            const f32x16 s = acc0 + acc1;
            #pragma unroll
            for (int r = 0; r < 16; r++) {
                const int row = wr * 32 + 4 * (l >> 5) + (r & 3) + 8 * (r >> 2);
                zbk[row * 64 + ((c4i ^ (row & 15)) << 2) + cr] = s[r];
            }
        }
        __syncthreads();                       // SYNC-2: zb ready, x drained

        // E: fused peephole cell (i, j, f, o); z = zb0 + zb1; 4B agent h-store
        {
            if (t < len) {
                #pragma unroll
                for (int j = 0; j < 2; j++) {
                    const int u = eu0 + j;
                    const int zoff = erow * 64 + ((u ^ (erow & 15)) << 2);
                    const float4 za = *(const float4*)&zb0[zoff];
                    const float4 zc = *(const float4*)&zb1[zoff];
                    const float zi = za.x + zc.x, zj = za.y + zc.y;
                    const float zf = za.z + zc.z, zo = za.w + zc.w;
                    const float cp = cc[j];
                    const float bi = j ? bi1 : bi0, bj = j ? bj1 : bj0;
                    const float bf = j ? bf1 : bf0, bo = j ? bo1 : bo0;
                    const float wiv = j ? wi1 : wi0, wfv = j ? wf1 : wf0, wov = j ? wo1 : wo0;
                    const float ig = sigmf(zi + bi + wiv * cp);
                    const float jg = tanhfast(zj + bj);
                    const float fg = sigmf(zf + bf + 2.0f + wfv * cp);
                    const float cn = fg * cp + ig * jg;
                    const float og = sigmf(zo + bo + wov * cn);
                    cc[j] = cn;
                    hh[j] = og * tanhfast(cn);
                }
            }
            __hip_atomic_store((unsigned int*)&hbq[(size_t)(rb + erow) * HH + Ug0],
                               packh2(hh[0], hh[1]),
                               __ATOMIC_RELAXED, __HIP_MEMORY_SCOPE_AGENT);
        }
        __syncthreads();                       // SYNC-3: drains h stores

        // F: post own flag (single agent store; strictly after the drain)
        if (t < TT - 1 && tid == 0)
            __hip_atomic_store(&gflags[bc], (unsigned)(t + 1),
                               __ATOMIC_RELAXED, __HIP_MEMORY_SCOPE_AGENT);
    }
    // 160 steps (even): final h in hbA (q rows 0..255, r rows 256..511)
}

// ---------------------------------------------------------------------------
// q_proj[256,512] = h_q(fp16)[256,512] @ M[512,512]
__global__ __launch_bounds__(512) void proj_kernel(
    const unsigned short* __restrict__ h, const float* __restrict__ M,
    float* __restrict__ qp)
{
    const int i = blockIdx.x;
    const int j = threadIdx.x;
    float s = 0.0f;
    for (int k = 0; k < HH; k++) s += h2f(h[(size_t)i * HH + k]) * M[(size_t)k * HH + j];
    qp[(size_t)i * HH + j] = s;
}

// C[256,256] = A[256,512] @ B(fp16)[256,512]^T
__global__ __launch_bounds__(256) void nt_gemm(
    const float* __restrict__ A,
    const unsigned short* __restrict__ B0, const unsigned short* __restrict__ B1,
    float* __restrict__ C0, float* __restrict__ C1)
{
    const unsigned short* Bm = blockIdx.z ? B1 : B0;
    float* Cm                = blockIdx.z ? C1 : C0;
    __shared__ float sA[16][17];
    __shared__ float sB[16][17];
    const int ti = threadIdx.x >> 4;
    const int tj = threadIdx.x & 15;
    const int ib = blockIdx.y * 16;
    const int jb = blockIdx.x * 16;
    float acc = 0.0f;
    for (int kk = 0; kk < HH; kk += 16) {
        sA[ti][tj] = A[(size_t)(ib + ti) * HH + kk + tj];
        sB[ti][tj] = h2f(Bm[(size_t)(jb + ti) * HH + kk + tj]);
        __syncthreads();
        #pragma unroll
        for (int k = 0; k < 16; k++) acc += sA[ti][k] * sB[tj][k];
        __syncthreads();
    }
    Cm[(size_t)(ib + ti) * 256 + jb + tj] = acc;
}

__global__ void diag_kernel(const float* __restrict__ dist, float* __restrict__ pos) {
    int i = threadIdx.x;
    pos[i] = dist[(size_t)i * 256 + i];
}

// ---------------------------------------------------------------------------
extern "C" void kernel_launch(void* const* d_in, const int* in_sizes, int n_in,
                              void* d_out, int out_size, void* d_ws, size_t ws_size,
                              hipStream_t stream) {
    const int*   qids = (const int*)d_in[0];
    const int*   rids = (const int*)d_in[1];
    const int*   qlen = (const int*)d_in[2];
    const int*   rlen = (const int*)d_in[3];
    const float* emb  = (const float*)d_in[4];
    const float* W    = (const float*)d_in[5];
    const float* bias = (const float*)d_in[6];
    const float* wi   = (const float*)d_in[7];
    const float* wf   = (const float*)d_in[8];
    const float* wo   = (const float*)d_in[9];
    const float* M    = (const float*)d_in[10];

    float* out       = (float*)d_out;
    float* distances = out;
    float* echo      = out + 256 * 256;
    float* pos       = out + 2 * 256 * 256;

    char* ws = (char*)d_ws;
    unsigned short* Wt   = (unsigned short*)(ws);                 // 3,145,728 B
    unsigned short* xseq = (unsigned short*)(ws + 3145728);       // 41,943,040 B
    unsigned short* hbA  = (unsigned short*)(ws + 45088768);      // 524,288 B
    unsigned short* hbB  = (unsigned short*)(ws + 45613056);      // 524,288 B
    float*          qp   = (float*)(ws + 46137344);               // 524,288 B
    unsigned int*   bar  = (unsigned int*)(ws + 46661632);        // 4,096 B

    const int SMEM = 131072;   // 6*16KB chunk bufs + 2*16KB z
    hipFuncSetAttribute((const void*)lstm_persist,
                        hipFuncAttributeMaxDynamicSharedMemorySize, SMEM);

    transposeW<<<dim3(64, 24), dim3(256), 0, stream>>>(W, Wt);
    xprep<<<dim3(TT * B2 / 4), dim3(256), 0, stream>>>(emb, qids, rids, xseq);
    hipMemsetAsync(hbA, 0, 524288, stream);
    hipMemsetAsync(bar, 0, 4096, stream);

    lstm_persist<<<dim3(256), dim3(512), SMEM, stream>>>(
        Wt, xseq, bias, wi, wf, wo, qlen, rlen, hbA, hbB, bar);

    proj_kernel<<<dim3(256), dim3(512), 0, stream>>>(hbA, M, qp);
    nt_gemm<<<dim3(16, 16, 2), dim3(256), 0, stream>>>(
        qp, hbA + (size_t)BQ * HH /*r_enc*/, hbA /*q_enc*/, distances, echo);
    diag_kernel<<<dim3(1), dim3(256), 0, stream>>>(distances, pos);
}

// Round 17
// 580.276 us; speedup vs baseline: 1.0353x; 1.0353x over previous
//
#include <hip/hip_runtime.h>
#include <math.h>

#define TT 160
#define EE 256
#define HH 512
#define KK 768
#define B2 512
#define BQ 256
#define N4 2048

typedef __attribute__((ext_vector_type(8)))  _Float16 half8;
typedef __attribute__((ext_vector_type(16))) float f32x16;

__device__ inline unsigned short f2h(float x){ union{_Float16 h; unsigned short u;}v; v.h=(_Float16)x; return v.u; }
__device__ inline float h2f(unsigned short u){ union{_Float16 h; unsigned short u;}v; v.u=u; return (float)v.h; }
__device__ inline unsigned int packh2(float a,float b){ union{_Float16 h[2]; unsigned int u;}v; v.h[0]=(_Float16)a; v.h[1]=(_Float16)b; return v.u; }

#define LOG2E 1.44269504088896f
__device__ inline float sigmf(float x){
    return __builtin_amdgcn_rcpf(1.0f + __builtin_amdgcn_exp2f(-LOG2E * x));
}
__device__ inline float tanhfast(float x){
    return 1.0f - 2.0f * __builtin_amdgcn_rcpf(__builtin_amdgcn_exp2f(2.0f * LOG2E * x) + 1.0f);
}

// cached (L1/L2) global->LDS, 16B/lane
__device__ inline void gload_lds16_c(const void* g, void* l){
    __builtin_amdgcn_global_load_lds(
        (const __attribute__((address_space(1))) void*)g,
        (__attribute__((address_space(3))) void*)l, 16, 0, 0);
}
// device-coherent global->LDS: SC0|SC1 (read the coherence point)
__device__ inline void gload_lds16_sc(const void* g, void* l){
    __builtin_amdgcn_global_load_lds(
        (const __attribute__((address_space(1))) void*)g,
        (__attribute__((address_space(3))) void*)l, 16, 0, 0x11);
}

// ---------------------------------------------------------------------------
// Wt[unit*4+gate][k] = fp16(W[k][gate*512+unit])   (gates interleaved per unit)
__global__ __launch_bounds__(256) void transposeW(const float* __restrict__ W,
                                                  unsigned short* __restrict__ Wt) {
    __shared__ float tile[32][33];
    const int tx = threadIdx.x & 31, ty = threadIdx.x >> 5;
    const int cb = blockIdx.x * 32;
    const int kb = blockIdx.y * 32;
    #pragma unroll
    for (int j = 0; j < 4; j++)
        tile[ty + j * 8][tx] = W[(size_t)(kb + ty + j * 8) * N4 + cb + tx];
    __syncthreads();
    #pragma unroll
    for (int j = 0; j < 4; j++) {
        int cl = ty + j * 8;
        int col = cb + cl;
        int gate = col >> 9, unit = col & 511;
        Wt[(size_t)(unit * 4 + gate) * KK + kb + tx] = f2h(tile[tx][cl]);
    }
}

// ---------------------------------------------------------------------------
// xseq[t*512+row][k] = fp16(emb[ids[row][t]][k])  — one wave per (t,row)
__global__ __launch_bounds__(256) void xprep(const float* __restrict__ emb,
                                             const int* __restrict__ qids,
                                             const int* __restrict__ rids,
                                             unsigned short* __restrict__ xseq) {
    const int widx = blockIdx.x * 4 + (threadIdx.x >> 6);
    const int lane = threadIdx.x & 63;
    const int row  = widx & 511;
    const int t    = widx >> 9;
    const int id   = (row < BQ) ? qids[row * TT + t] : rids[(row - BQ) * TT + t];
    const float4 f = *(const float4*)&emb[(size_t)id * EE + lane * 4];
    *(uint2*)&xseq[(size_t)widx * EE + lane * 4] =
        make_uint2(packh2(f.x, f.y), packh2(f.z, f.w));
}

// ---------------------------------------------------------------------------
// Persistent LSTM (validated r12 design — the session optimum, reproduced
// twice at 538 µs). 256 blocks x 512 threads (8 waves = 2/SIMD).
// Block (g=bid&7, bc=bid>>3): rows [g*64,+64), units [bc*16,+16).
// Wave (wr,wc,kg): rows wr*32, cols' wc*32, K-half kg. W K-half
// register-resident (24 half8 = 96 VGPR). K-half partials to separate
// zb0/zb1; cell sums them. Barrier: 32 per-block flags/group; post = 1
// agent store, observe = 32-lane coalesced poll (wave 0 only — all-wave
// polling congests IF$, r16 lesson). h exchange: agent 4B stores +
// sc0|sc1 gload_lds. Stages live in exactly one barrier interval
// (each __syncthreads drains vmcnt(0) — r13 lesson); gload_lds is never
// issued ahead of same-interval ds_reads (r8/r16 lesson).
__global__ __launch_bounds__(512, 1) void lstm_persist(
    const unsigned short* __restrict__ Wt,
    const unsigned short* __restrict__ xseq,
    const float* __restrict__ bias,
    const float* __restrict__ wi_, const float* __restrict__ wf_,
    const float* __restrict__ wo_,
    const int* __restrict__ qlen, const int* __restrict__ rlen,
    unsigned short* __restrict__ hbA, unsigned short* __restrict__ hbB,
    unsigned int* __restrict__ bar)   // bar[g*64 + bc] = flags; 8 groups
{
    extern __shared__ char smem[];              // 6*16KB bufs + 2*16KB zb
    float* zb0 = (float*)(smem + 98304);        // [64][64] f32, f4-col swz (kg=0)
    float* zb1 = zb0 + 4096;                    // (kg=1)

    const int tid = threadIdx.x;
    const int bid = blockIdx.x;
    const int g   = bid & 7;
    const int bc  = bid >> 3;
    const int rb  = g * 64;
    unsigned int* gflags = bar + g * 64;
    const int l = tid & 63, w = tid >> 6;
    const int wr = (w >> 2) & 1, wc = (w >> 1) & 1, kg = w & 1;

    // ---- resident W fragments: wave's 32 cols' x its K-half (24 half8)
    half8 wfrag[24];
    {
        const int colp = bc * 64 + wc * 32 + (l & 31);
        const unsigned short* wrow = Wt + (size_t)colp * KK + kg * 64 + (l >> 5) * 8;
        #pragma unroll
        for (int c = 0; c < 6; c++)
            #pragma unroll
            for (int f4 = 0; f4 < 4; f4++)
                wfrag[c * 4 + f4] = *(const half8*)(wrow + c * 128 + f4 * 16);
    }

    // ---- epilogue: thread owns 1 row (erow) x 2 contiguous units
    const int erow = tid >> 3;
    const int eu0  = (tid & 7) * 2;
    const int Ug0  = bc * 16 + eu0;
    const float bi0 = bias[Ug0],        bi1 = bias[Ug0 + 1];
    const float bj0 = bias[HH + Ug0],   bj1 = bias[HH + Ug0 + 1];
    const float bf0 = bias[2*HH + Ug0], bf1 = bias[2*HH + Ug0 + 1];
    const float bo0 = bias[3*HH + Ug0], bo1 = bias[3*HH + Ug0 + 1];
    const float wi0 = wi_[Ug0], wi1 = wi_[Ug0 + 1];
    const float wf0 = wf_[Ug0], wf1 = wf_[Ug0 + 1];
    const float wo0 = wo_[Ug0], wo1 = wo_[Ug0 + 1];
    const int len = (rb + erow < BQ) ? qlen[rb + erow] : rlen[rb + erow - BQ];
    float cc[2] = {0.f, 0.f}, hh[2] = {0.f, 0.f};

    // stage K-chunk tk of step tt into buf tk. Wave w stages rows [w*8,+8).
    // LDS dest linear; XOR-swizzle folded into per-lane SOURCE address.
    auto stage = [&](int tk, int tt, const unsigned short* hsrc) {
        char* base = smem + tk * 16384;
        #pragma unroll
        for (int i2 = 0; i2 < 2; i2++) {
            const int rowbase = w * 8 + i2 * 4;
            const int row = rowbase + (l >> 4);
            const int cch = l & 15;
            const int srcElem = (cch ^ (row & 15)) << 3;
            if (tk < 2) {
                const unsigned short* src =
                    xseq + ((size_t)(tt * B2 + rb + row) * EE + tk * 128 + srcElem);
                gload_lds16_c(src, base + rowbase * 256);
            } else {
                const unsigned short* src =
                    hsrc + ((size_t)(rb + row) * HH + (tk - 2) * 128 + srcElem);
                gload_lds16_sc(src, base + rowbase * 256);
            }
        }
    };

    // wave computes its K-half of chunk tk: 4 MFMAs
    auto compute = [&](int tk, f32x16* a0, f32x16* a1) {
        const char* Ab = smem + tk * 16384;
        const int ra = wr * 32 + (l & 31);
        #pragma unroll
        for (int f4 = 0; f4 < 4; f4++) {
            const int kc = kg * 8 + f4 * 2 + (l >> 5);
            half8 av = *(const half8*)(Ab + ra * 256 + ((kc ^ (ra & 15)) << 4));
            if (f4 & 1) *a1 = __builtin_amdgcn_mfma_f32_32x32x16_f16(av, wfrag[tk * 4 + f4], *a1, 0, 0, 0);
            else        *a0 = __builtin_amdgcn_mfma_f32_32x32x16_f16(av, wfrag[tk * 4 + f4], *a0, 0, 0, 0);
        }
    };

    // prologue: stage step-0 x chunks
    stage(0, 0, hbA);
    stage(1, 0, hbA);
    __syncthreads();

    #pragma unroll 1
    for (int t = 0; t < TT; t++) {
        const unsigned short* hbp = (t & 1) ? hbB : hbA;
        unsigned short* hbq       = (t & 1) ? hbA : hbB;
        f32x16 acc0 = {0,0,0,0,0,0,0,0,0,0,0,0,0,0,0,0};
        f32x16 acc1 = {0,0,0,0,0,0,0,0,0,0,0,0,0,0,0,0};

        // A: x contributions (bufs 0,1 staged last iteration); overlap the
        // flag-wait (32 lanes of wave 0, one coalesced IF$ poll per iter)
        compute(0, &acc0, &acc1);
        compute(1, &acc0, &acc1);
        if (t > 0 && tid < 32) {
            while (__hip_atomic_load(&gflags[tid], __ATOMIC_RELAXED,
                                     __HIP_MEMORY_SCOPE_AGENT) < (unsigned)t)
                __builtin_amdgcn_s_sleep(1);
        }
        __syncthreads();                       // h(t) readable; x computes done

        // B: issue ALL stages back-to-back — one barrier interval, one drain
        stage(2, t, hbp);
        stage(3, t, hbp);
        stage(4, t, hbp);
        stage(5, t, hbp);
        if (t < TT - 1) {
            stage(0, t + 1, hbp);              // x of t+1 (cached, no dep)
            stage(1, t + 1, hbp);
        }
        __syncthreads();                       // one vmcnt drain for all

        // C: h-part MFMAs (W resident; 2 waves/SIMD hide ds_read latency)
        compute(2, &acc0, &acc1);
        compute(3, &acc0, &acc1);
        compute(4, &acc0, &acc1);
        compute(5, &acc0, &acc1);

        // D: z partials into per-K-half regions, float4-column XOR swizzle
        {
            float* zbk = kg ? zb1 : zb0;
            const int colb = wc * 32 + (l & 31);
            const int c4i = colb >> 2, cr = colb & 3;
            const f32x16 s = acc0 + acc1;
            #pragma unroll
            for (int r = 0; r < 16; r++) {
                const int row = wr * 32 + 4 * (l >> 5) + (r & 3) + 8 * (r >> 2);
                zbk[row * 64 + ((c4i ^ (row & 15)) << 2) + cr] = s[r];
            }
        }
        __syncthreads();                       // zb ready

        // E: fused peephole cell (i, j, f, o); z = zb0 + zb1; 4B agent h-store
        {
            if (t < len) {
                #pragma unroll
                for (int j = 0; j < 2; j++) {
                    const int u = eu0 + j;
                    const int zoff = erow * 64 + ((u ^ (erow & 15)) << 2);
                    const float4 za = *(const float4*)&zb0[zoff];
                    const float4 zc = *(const float4*)&zb1[zoff];
                    const float zi = za.x + zc.x, zj = za.y + zc.y;
                    const float zf = za.z + zc.z, zo = za.w + zc.w;
                    const float cp = cc[j];
                    const float bi = j ? bi1 : bi0, bj = j ? bj1 : bj0;
                    const float bf = j ? bf1 : bf0, bo = j ? bo1 : bo0;
                    const float wiv = j ? wi1 : wi0, wfv = j ? wf1 : wf0, wov = j ? wo1 : wo0;
                    const float ig = sigmf(zi + bi + wiv * cp);
                    const float jg = tanhfast(zj + bj);
                    const float fg = sigmf(zf + bf + 2.0f + wfv * cp);
                    const float cn = fg * cp + ig * jg;
                    const float og = sigmf(zo + bo + wov * cn);
                    cc[j] = cn;
                    hh[j] = og * tanhfast(cn);
                }
            }
            __hip_atomic_store((unsigned int*)&hbq[(size_t)(rb + erow) * HH + Ug0],
                               packh2(hh[0], hh[1]),
                               __ATOMIC_RELAXED, __HIP_MEMORY_SCOPE_AGENT);
        }
        __syncthreads();                       // drains h stores (vmcnt 0)

        // F: post own flag (single agent store; no RMW, no hotspot)
        if (t < TT - 1 && tid == 0)
            __hip_atomic_store(&gflags[bc], (unsigned)(t + 1),
                               __ATOMIC_RELAXED, __HIP_MEMORY_SCOPE_AGENT);
    }
    // 160 steps (even): final h in hbA (q rows 0..255, r rows 256..511)
}

// ---------------------------------------------------------------------------
// q_proj[256,512] = h_q(fp16)[256,512] @ M[512,512]
__global__ __launch_bounds__(512) void proj_kernel(
    const unsigned short* __restrict__ h, const float* __restrict__ M,
    float* __restrict__ qp)
{
    const int i = blockIdx.x;
    const int j = threadIdx.x;
    float s = 0.0f;
    for (int k = 0; k < HH; k++) s += h2f(h[(size_t)i * HH + k]) * M[(size_t)k * HH + j];
    qp[(size_t)i * HH + j] = s;
}

// C[256,256] = A[256,512] @ B(fp16)[256,512]^T
__global__ __launch_bounds__(256) void nt_gemm(
    const float* __restrict__ A,
    const unsigned short* __restrict__ B0, const unsigned short* __restrict__ B1,
    float* __restrict__ C0, float* __restrict__ C1)
{
    const unsigned short* Bm = blockIdx.z ? B1 : B0;
    float* Cm                = blockIdx.z ? C1 : C0;
    __shared__ float sA[16][17];
    __shared__ float sB[16][17];
    const int ti = threadIdx.x >> 4;
    const int tj = threadIdx.x & 15;
    const int ib = blockIdx.y * 16;
    const int jb = blockIdx.x * 16;
    float acc = 0.0f;
    for (int kk = 0; kk < HH; kk += 16) {
        sA[ti][tj] = A[(size_t)(ib + ti) * HH + kk + tj];
        sB[ti][tj] = h2f(Bm[(size_t)(jb + ti) * HH + kk + tj]);
        __syncthreads();
        #pragma unroll
        for (int k = 0; k < 16; k++) acc += sA[ti][k] * sB[tj][k];
        __syncthreads();
    }
    Cm[(size_t)(ib + ti) * 256 + jb + tj] = acc;
}

__global__ void diag_kernel(const float* __restrict__ dist, float* __restrict__ pos) {
    int i = threadIdx.x;
    pos[i] = dist[(size_t)i * 256 + i];
}

// ---------------------------------------------------------------------------
extern "C" void kernel_launch(void* const* d_in, const int* in_sizes, int n_in,
                              void* d_out, int out_size, void* d_ws, size_t ws_size,
                              hipStream_t stream) {
    const int*   qids = (const int*)d_in[0];
    const int*   rids = (const int*)d_in[1];
    const int*   qlen = (const int*)d_in[2];
    const int*   rlen = (const int*)d_in[3];
    const float* emb  = (const float*)d_in[4];
    const float* W    = (const float*)d_in[5];
    const float* bias = (const float*)d_in[6];
    const float* wi   = (const float*)d_in[7];
    const float* wf   = (const float*)d_in[8];
    const float* wo   = (const float*)d_in[9];
    const float* M    = (const float*)d_in[10];

    float* out       = (float*)d_out;
    float* distances = out;
    float* echo      = out + 256 * 256;
    float* pos       = out + 2 * 256 * 256;

    char* ws = (char*)d_ws;
    unsigned short* Wt   = (unsigned short*)(ws);                 // 3,145,728 B
    unsigned short* xseq = (unsigned short*)(ws + 3145728);       // 41,943,040 B
    unsigned short* hbA  = (unsigned short*)(ws + 45088768);      // 524,288 B
    unsigned short* hbB  = (unsigned short*)(ws + 45613056);      // 524,288 B
    float*          qp   = (float*)(ws + 46137344);               // 524,288 B
    unsigned int*   bar  = (unsigned int*)(ws + 46661632);        // 4,096 B

    const int SMEM = 131072;   // 6*16KB chunk bufs + 2*16KB z
    hipFuncSetAttribute((const void*)lstm_persist,
                        hipFuncAttributeMaxDynamicSharedMemorySize, SMEM);

    transposeW<<<dim3(64, 24), dim3(256), 0, stream>>>(W, Wt);
    xprep<<<dim3(TT * B2 / 4), dim3(256), 0, stream>>>(emb, qids, rids, xseq);
    hipMemsetAsync(hbA, 0, 524288, stream);
    hipMemsetAsync(bar, 0, 4096, stream);

    lstm_persist<<<dim3(256), dim3(512), SMEM, stream>>>(
        Wt, xseq, bias, wi, wf, wo, qlen, rlen, hbA, hbB, bar);

    proj_kernel<<<dim3(256), dim3(512), 0, stream>>>(hbA, M, qp);
    nt_gemm<<<dim3(16, 16, 2), dim3(256), 0, stream>>>(
        qp, hbA + (size_t)BQ * HH /*r_enc*/, hbA /*q_enc*/, distances, echo);
    diag_kernel<<<dim3(1), dim3(256), 0, stream>>>(distances, pos);
}